// Round 5
// baseline (312.953 us; speedup 1.0000x reference)
//
#include <hip/hip_runtime.h>
#include <hip/hip_bf16.h>
#include <stdint.h>

// CovPool: B=32, N=16384, D=64 fp32 -> per-batch cov (64x64), triu, globally
// sorted 66560 fp32 outputs.
// R12: cov was latency-bound on VMEM request count (64x dword loads/lane,
// 29% HBM, VALUBusy 8%). Column-permutation trick: relabel MFMA column c to
// actual dim p(c)=4*(c&15)+(c>>4), so each lane's 4 fragment values for
// t=0..3 are 4 consecutive floats -> ONE global_load_dwordx4 (16 loads/lane
// total, 4x fewer requests, full 256B row per 16-lane group). Permutation is
// undone in reduce/finalize epilogues (cov is permutation-equivariant).
// Tail = verified R7 hierarchical structure.
//
// Partial-path ws layout:
//   hist      [262144 u32]      @ 0
//   counts    [16 u32]          @ 1048576
//   offsets   [262144 u32]      @ 1048640
//   blocksums [1024 u32]        @ 2097216
//   tri       [66560 f32]       @ 2101312
//   wl_small  [33280 uint2]     @ 2367552
//   wl_large  [4096 uint2]      @ 2633792
//   partials  [2048][2624] f32  @ 2666560  (ends 24162368)

#define BATCHES 32
#define NSAMP   16384
#define DIM     64
#define LAMBDA  0.01f
#define NTRI    2080
#define NOUT    (BATCHES * NTRI)   // 66560

#define CHUNKS_PER_BATCH 64
#define SAMP_PER_BLOCK   (NSAMP / CHUNKS_PER_BATCH)  // 256
#define SAMP_PER_WAVE    (SAMP_PER_BLOCK / 4)        // 64
#define PARTIAL_STRIDE   2624                        // 2560 S + 64 msum

#define KEY_SHIFT 14                                 // top 18 bits
#define NBUCKET   (1 << 18)
#define SMALL_MAX 64u
#define SORT_CAP  8192

typedef __attribute__((ext_vector_type(4))) float f32x4;
typedef __attribute__((ext_vector_type(8))) short s16x8;

__device__ __forceinline__ uint32_t sort_key(float v) {
    uint32_t u = __builtin_bit_cast(uint32_t, v);
    return u ^ (uint32_t)(((int32_t)u >> 31) | 0x80000000u);
}

__device__ __forceinline__ uint32_t cvt_pk_bf16(float lo, float hi) {
    __hip_bfloat162 bb = __float22bfloat162_rn(make_float2(lo, hi));  // v_cvt_pk_bf16_f32
    uint32_t u;
    __builtin_memcpy(&u, &bb, 4);
    return u;
}

// permuted MFMA column index c (= t*16 + l15) -> actual dimension
__device__ __forceinline__ int perm_d(int c) { return 4 * (c & 15) + (c >> 4); }

__constant__ const int c_tmi[10] = {0, 0, 0, 0, 1, 1, 1, 2, 2, 3};
__constant__ const int c_tni[10] = {0, 1, 2, 3, 1, 2, 3, 2, 3, 3};

// ============ shared device body: dwordx4 all-up-front MFMA K-loop ===========
struct CovLds {
    float red[2][64][41];     // 20992 B (epilogue tree)
    float msum_red[4][64];    // 1024 B
};

template <typename EpilogueFn>
__device__ __forceinline__ void cov_body(const float* __restrict__ x, CovLds& L,
                                         EpilogueFn epi) {
    const int tid  = threadIdx.x;
    const int wave = tid >> 6;
    const int lane = tid & 63;
    const int b     = blockIdx.x / CHUNKS_PER_BATCH;
    const int chunk = blockIdx.x % CHUNKS_PER_BATCH;
    const int n_start = chunk * SAMP_PER_BLOCK + wave * SAMP_PER_WAVE;

    const int l15  = lane & 15;
    const int quad = lane >> 4;

    // lane (quad,l15) loads x[s0 + quad*8 + j][4*l15 .. 4*l15+3] in ONE
    // dwordx4; element t is permuted column c=t*16+l15 (actual dim 4*l15+t).
    const float* xw = x + ((size_t)b * NSAMP + n_start) * DIM
                        + quad * 8 * DIM + 4 * l15;

    f32x4 acc[10];
#pragma unroll
    for (int t = 0; t < 10; ++t) acc[t] = (f32x4){0.f, 0.f, 0.f, 0.f};
    float sum_t[4] = {0.f, 0.f, 0.f, 0.f};

    f32x4 va[8], vb[8];

    auto loadit = [&](f32x4 (&v)[8], int kc) {
        const float* xs = xw + kc * 32 * DIM;
#pragma unroll
        for (int j = 0; j < 8; ++j)
            v[j] = *reinterpret_cast<const f32x4*>(xs + j * DIM);  // 8 x4 loads
    };

    auto compute = [&](f32x4 (&v)[8]) {
#pragma unroll
        for (int j = 0; j < 8; ++j)
#pragma unroll
            for (int t = 0; t < 4; ++t) sum_t[t] += v[j][t];

        s16x8 frag[4];
#pragma unroll
        for (int t = 0; t < 4; ++t) {
            uint32_t pk0 = cvt_pk_bf16(v[0][t], v[1][t]);
            uint32_t pk1 = cvt_pk_bf16(v[2][t], v[3][t]);
            uint32_t pk2 = cvt_pk_bf16(v[4][t], v[5][t]);
            uint32_t pk3 = cvt_pk_bf16(v[6][t], v[7][t]);
            frag[t] = __builtin_bit_cast(s16x8, make_uint4(pk0, pk1, pk2, pk3));
        }

        acc[0] = __builtin_amdgcn_mfma_f32_16x16x32_bf16(frag[0], frag[0], acc[0], 0, 0, 0);
        acc[1] = __builtin_amdgcn_mfma_f32_16x16x32_bf16(frag[0], frag[1], acc[1], 0, 0, 0);
        acc[2] = __builtin_amdgcn_mfma_f32_16x16x32_bf16(frag[0], frag[2], acc[2], 0, 0, 0);
        acc[3] = __builtin_amdgcn_mfma_f32_16x16x32_bf16(frag[0], frag[3], acc[3], 0, 0, 0);
        acc[4] = __builtin_amdgcn_mfma_f32_16x16x32_bf16(frag[1], frag[1], acc[4], 0, 0, 0);
        acc[5] = __builtin_amdgcn_mfma_f32_16x16x32_bf16(frag[1], frag[2], acc[5], 0, 0, 0);
        acc[6] = __builtin_amdgcn_mfma_f32_16x16x32_bf16(frag[1], frag[3], acc[6], 0, 0, 0);
        acc[7] = __builtin_amdgcn_mfma_f32_16x16x32_bf16(frag[2], frag[2], acc[7], 0, 0, 0);
        acc[8] = __builtin_amdgcn_mfma_f32_16x16x32_bf16(frag[2], frag[3], acc[8], 0, 0, 0);
        acc[9] = __builtin_amdgcn_mfma_f32_16x16x32_bf16(frag[3], frag[3], acc[9], 0, 0, 0);
    };

    // 2 chunks per wave: issue all 16 x4-loads before any compute (max MLP).
    loadit(va, 0);
    loadit(vb, 1);
    compute(va);        // waits only on va's 8 loads
    compute(vb);

    // ---- per-dim mean partials (permuted index c = t*16+l15) ----
#pragma unroll
    for (int t = 0; t < 4; ++t) {
        sum_t[t] += __shfl_xor(sum_t[t], 16, 64);
        sum_t[t] += __shfl_xor(sum_t[t], 32, 64);
    }
    if (lane < 16) {
#pragma unroll
        for (int t = 0; t < 4; ++t) L.msum_red[wave][t * 16 + lane] = sum_t[t];
    }

    // ---- in-block tree reduction of 4 waves into wave0 ----
    __syncthreads();
    if (wave == 1 || wave == 3) {
        int slot = wave >> 1;
#pragma unroll
        for (int t = 0; t < 10; ++t)
#pragma unroll
            for (int r = 0; r < 4; ++r) L.red[slot][lane][t * 4 + r] = acc[t][r];
    }
    __syncthreads();
    if (wave == 0 || wave == 2) {
        int slot = wave >> 1;
#pragma unroll
        for (int t = 0; t < 10; ++t)
#pragma unroll
            for (int r = 0; r < 4; ++r) acc[t][r] += L.red[slot][lane][t * 4 + r];
    }
    __syncthreads();
    if (wave == 2) {
#pragma unroll
        for (int t = 0; t < 10; ++t)
#pragma unroll
            for (int r = 0; r < 4; ++r) L.red[0][lane][t * 4 + r] = acc[t][r];
    }
    __syncthreads();
    if (wave == 0) {
#pragma unroll
        for (int t = 0; t < 10; ++t)
#pragma unroll
            for (int r = 0; r < 4; ++r) acc[t][r] += L.red[0][lane][t * 4 + r];
        float msum_tot = L.msum_red[0][lane] + L.msum_red[1][lane] +
                         L.msum_red[2][lane] + L.msum_red[3][lane];
        epi(b, lane, quad, l15, acc, msum_tot);
    }
}

// ---------------- K1p: partial-store variant + hist zeroing ------------------
__global__ __launch_bounds__(256, 3) void cov_kernel_p(const float* __restrict__ x,
                                                       float* __restrict__ partials,
                                                       uint32_t* __restrict__ hist,
                                                       uint32_t* __restrict__ counts) {
    // fold the hist/counts zeroing in: first 1024 blocks cover NBUCKET
    if (blockIdx.x < NBUCKET / 256)
        hist[blockIdx.x * 256 + threadIdx.x] = 0u;
    if (blockIdx.x == 0 && threadIdx.x < 16) counts[threadIdx.x] = 0u;

    __shared__ CovLds L;
    float* Pb = partials + (size_t)blockIdx.x * PARTIAL_STRIDE;
    cov_body(x, L, [&](int b, int lane, int quad, int l15, f32x4* acc, float msum) {
#pragma unroll
        for (int t = 0; t < 10; ++t)
#pragma unroll
            for (int r = 0; r < 4; ++r)
                Pb[t * 256 + r * 64 + lane] = acc[t][r];   // coalesced (permuted space)
        Pb[2560 + lane] = msum;
    });
}

// ---------------- K1a: atomic fallback variant -------------------------------
__global__ __launch_bounds__(256, 3) void cov_kernel_a(const float* __restrict__ x,
                                                       float* __restrict__ S,
                                                       float* __restrict__ Msum) {
    __shared__ CovLds L;
    cov_body(x, L, [&](int b, int lane, int quad, int l15, f32x4* acc, float msum) {
        float* Sb = S + b * DIM * DIM;
#pragma unroll
        for (int t = 0; t < 10; ++t) {
            const bool diag_tile = (c_tmi[t] == c_tni[t]);
#pragma unroll
            for (int r = 0; r < 4; ++r) {
                int rp = c_tmi[t] * 16 + quad * 4 + r;   // permuted row
                int cp = c_tni[t] * 16 + l15;            // permuted col
                int ar = perm_d(rp), ac = perm_d(cp);
                if (diag_tile && ar > ac) continue;      // mirror covers it
                int r0 = min(ar, ac), c0 = max(ar, ac);
                atomicAdd(&Sb[r0 * DIM + c0], acc[t][r]);
            }
        }
        atomicAdd(&Msum[b * DIM + perm_d(lane)], msum);
    });
}

// ---------------- K2p: reduce partials + finalize + histogram (320 blocks) ---
__global__ __launch_bounds__(256) void reduce_kernel(const float* __restrict__ partials,
                                                     float* __restrict__ tri,
                                                     uint32_t* __restrict__ hist) {
    const int b = blockIdx.x / 10, k = blockIdx.x % 10;
    const int tid = threadIdx.x;
    __shared__ float msum[DIM];   // permuted-space index
    const float* P0 = partials + (size_t)b * CHUNKS_PER_BATCH * PARTIAL_STRIDE;

    if (tid < DIM) {
        float ms = 0.f;
#pragma unroll 8
        for (int c = 0; c < CHUNKS_PER_BATCH; ++c)
            ms += P0[c * PARTIAL_STRIDE + 2560 + tid];
        msum[tid] = ms;
    }

    float a = 0.f;
#pragma unroll 8
    for (int c = 0; c < CHUNKS_PER_BATCH; ++c)
        a += P0[c * PARTIAL_STRIDE + k * 256 + tid];   // coalesced
    __syncthreads();

    const int r = tid >> 6, lane = tid & 63, quad = lane >> 4, l15 = lane & 15;
    const int rp = c_tmi[k] * 16 + quad * 4 + r;       // permuted row
    const int cp = c_tni[k] * 16 + l15;                // permuted col
    const int ar = perm_d(rp), ac = perm_d(cp);        // actual dims
    const bool diag_tile = (c_tmi[k] == c_tni[k]);
    if (!(diag_tile && ar > ac)) {
        const int r0 = min(ar, ac), c0 = max(ar, ac);
        float v = (a - msum[rp] * msum[cp] * (1.0f / NSAMP)) * (1.0f / (NSAMP - 1));
        if (r0 == c0) v += LAMBDA;
        int p = r0 * 64 - (r0 * (r0 + 1)) / 2 + c0;
        tri[b * NTRI + p] = v;
        atomicAdd(&hist[sort_key(v) >> KEY_SHIFT], 1u);
    }
}

// ---------------- K2a: finalize (atomic fallback path) -----------------------
__global__ void finalize_kernel(const float* __restrict__ S,
                                const float* __restrict__ Msum,
                                float* __restrict__ tri,
                                uint32_t* __restrict__ hist) {
    int t = blockIdx.x * blockDim.x + threadIdx.x;
    int b = t >> 12, de = t & 4095, d = de >> 6, e = de & 63;
    if (d > e) return;
    float ssum = S[b * 4096 + d * 64 + e];
    float md = Msum[b * 64 + d], me = Msum[b * 64 + e];
    float v = (ssum - md * me * (1.0f / NSAMP)) * (1.0f / (NSAMP - 1));
    if (d == e) v += LAMBDA;
    int p = d * 64 - (d * (d + 1)) / 2 + e;
    tri[b * NTRI + p] = v;
    atomicAdd(&hist[sort_key(v) >> KEY_SHIFT], 1u);
}

// ---------------- K3a: per-256-bucket partial sums (1024 blocks) -------------
__global__ __launch_bounds__(256) void scanA_kernel(const uint32_t* __restrict__ hist,
                                                    uint32_t* __restrict__ blocksums) {
    __shared__ uint32_t s[256];
    int tid = threadIdx.x;
    s[tid] = hist[blockIdx.x * 256 + tid];
    __syncthreads();
    for (int off = 128; off > 0; off >>= 1) {
        if (tid < off) s[tid] += s[tid + off];
        __syncthreads();
    }
    if (tid == 0) blocksums[blockIdx.x] = s[0];
}

// ---------------- K3b: offsets + worklists (1024 blocks) ---------------------
__global__ __launch_bounds__(256) void scanB_kernel(const uint32_t* __restrict__ hist,
                                                    const uint32_t* __restrict__ blocksums,
                                                    uint32_t* __restrict__ offsets,
                                                    uint2* __restrict__ wl_small,
                                                    uint2* __restrict__ wl_large,
                                                    uint32_t* __restrict__ counts) {
    __shared__ uint32_t bs[256];
    __shared__ uint32_t sc[256];
    __shared__ uint32_t base_sh;
    int tid = threadIdx.x, bid = blockIdx.x;

    uint32_t b4[4]; uint32_t s4 = 0;
#pragma unroll
    for (int i = 0; i < 4; ++i) { b4[i] = blocksums[4 * tid + i]; s4 += b4[i]; }
    bs[tid] = s4;
    __syncthreads();
    for (int off = 1; off < 256; off <<= 1) {
        uint32_t a = (tid >= off) ? bs[tid - off] : 0u;
        __syncthreads();
        bs[tid] += a;
        __syncthreads();
    }
    if (tid == (bid >> 2)) {
        uint32_t base = (tid > 0) ? bs[tid - 1] : 0u;
        for (int i = 0; i < (bid & 3); ++i) base += b4[i];
        base_sh = base;
    }

    uint32_t v = hist[bid * 256 + tid];
    sc[tid] = v;
    __syncthreads();
    for (int off = 1; off < 256; off <<= 1) {
        uint32_t a = (tid >= off) ? sc[tid - off] : 0u;
        __syncthreads();
        sc[tid] += a;
        __syncthreads();
    }
    uint32_t excl = base_sh + sc[tid] - v;
    offsets[bid * 256 + tid] = excl;
    if (v >= 2u) {
        if (v <= SMALL_MAX) {
            uint32_t w = atomicAdd(&counts[0], 1u);
            wl_small[w] = make_uint2(excl, v);
        } else {
            uint32_t w = atomicAdd(&counts[1], 1u);
            wl_large[w] = make_uint2(excl, v);
        }
    }
}

// ---------------- K4: scatter into bucket positions --------------------------
__global__ void scatter_kernel(const float* __restrict__ tri,
                               uint32_t* __restrict__ offsets,
                               float* __restrict__ out) {
    int i = blockIdx.x * blockDim.x + threadIdx.x;
    if (i >= NOUT) return;
    float v = tri[i];
    uint32_t pos = atomicAdd(&offsets[sort_key(v) >> KEY_SHIFT], 1u);
    out[pos] = v;
}

// ---------------- K5: fused run cleanup (block-sort large, wave-sort small) --
__global__ __launch_bounds__(256) void runsort_kernel(float* __restrict__ out,
                                                      const uint2* __restrict__ wl_small,
                                                      const uint2* __restrict__ wl_large,
                                                      const uint32_t* __restrict__ counts) {
    __shared__ float buf[SORT_CAP];

    uint32_t nl = counts[1];
    for (uint32_t w = blockIdx.x; w < nl; w += gridDim.x) {
        uint2 ent = wl_large[w];
        uint32_t start = ent.x, cnt = ent.y;
        if (cnt > SORT_CAP) continue;
        uint32_t m = 1;
        while (m < cnt) m <<= 1;
        for (uint32_t i = threadIdx.x; i < m; i += blockDim.x)
            buf[i] = (i < cnt) ? out[start + i] : __builtin_inff();
        __syncthreads();
        for (uint32_t k = 2; k <= m; k <<= 1) {
            for (uint32_t j = k >> 1; j > 0; j >>= 1) {
                for (uint32_t i = threadIdx.x; i < m; i += blockDim.x) {
                    uint32_t ixj = i ^ j;
                    if (ixj > i) {
                        float a = buf[i], c = buf[ixj];
                        bool up = ((i & k) == 0u);
                        if ((a > c) == up) { buf[i] = c; buf[ixj] = a; }
                    }
                }
                __syncthreads();
            }
        }
        for (uint32_t i = threadIdx.x; i < cnt; i += blockDim.x)
            out[start + i] = buf[i];
        __syncthreads();
    }

    uint32_t ns = counts[0];
    int wave = threadIdx.x >> 6, lane = threadIdx.x & 63;
    for (uint32_t r = blockIdx.x * 4 + wave; r < ns; r += gridDim.x * 4) {
        uint2 e = wl_small[r];
        uint32_t start = e.x, cnt = e.y;
        float v = (lane < (int)cnt) ? out[start + lane] : __builtin_inff();
#pragma unroll
        for (uint32_t k = 2; k <= 64; k <<= 1)
            for (uint32_t j = k >> 1; j > 0; j >>= 1) {
                float p = __shfl_xor(v, (int)j, 64);
                bool keepmin = (((lane & k) == 0u) == ((lane & j) == 0u));
                v = keepmin ? fminf(v, p) : fmaxf(v, p);
            }
        if (lane < (int)cnt) out[start + lane] = v;
    }
}

// ---------------- shared tail launcher ---------------------------------------
static void launch_tail(uint32_t* hist, uint32_t* blocksums, uint32_t* offsets,
                        float* tri, uint2* wl_small, uint2* wl_large,
                        uint32_t* counts, float* out, hipStream_t stream) {
    scanA_kernel<<<NBUCKET / 256, 256, 0, stream>>>(hist, blocksums);
    scanB_kernel<<<NBUCKET / 256, 256, 0, stream>>>(hist, blocksums, offsets,
                                                    wl_small, wl_large, counts);
    scatter_kernel<<<(NOUT + 255) / 256, 256, 0, stream>>>(tri, offsets, out);
    runsort_kernel<<<1024, 256, 0, stream>>>(out, wl_small, wl_large, counts);
}

extern "C" void kernel_launch(void* const* d_in, const int* in_sizes, int n_in,
                              void* d_out, int out_size, void* d_ws, size_t ws_size,
                              hipStream_t stream) {
    const float* x = (const float*)d_in[0];
    float* out = (float*)d_out;
    char* ws = (char*)d_ws;

    const size_t NEED_P =
        2666560 + (size_t)BATCHES * CHUNKS_PER_BATCH * PARTIAL_STRIDE * 4;  // 24.2 MB

    if (ws_size >= NEED_P) {
        uint32_t* hist      = (uint32_t*)(ws);
        uint32_t* counts    = (uint32_t*)(ws + 1048576);
        uint32_t* offsets   = (uint32_t*)(ws + 1048640);
        uint32_t* blocksums = (uint32_t*)(ws + 2097216);
        float*    tri       = (float*)(ws + 2101312);
        uint2*    wl_small  = (uint2*)(ws + 2367552);
        uint2*    wl_large  = (uint2*)(ws + 2633792);
        float*    partials  = (float*)(ws + 2666560);

        // no memset: cov zeroes hist+counts itself
        cov_kernel_p<<<BATCHES * CHUNKS_PER_BATCH, 256, 0, stream>>>(x, partials, hist, counts);
        reduce_kernel<<<BATCHES * 10, 256, 0, stream>>>(partials, tri, hist);
        launch_tail(hist, blocksums, offsets, tri, wl_small, wl_large, counts, out, stream);
    } else {
        float*    S         = (float*)(ws);
        float*    Msum      = (float*)(ws + 524288);
        uint32_t* hist      = (uint32_t*)(ws + 532480);
        uint32_t* counts    = (uint32_t*)(ws + 1581056);
        uint32_t* offsets   = (uint32_t*)(ws + 1581120);
        uint32_t* blocksums = (uint32_t*)(ws + 2629696);
        float*    tri       = (float*)(ws + 2633792);
        uint2*    wl_small  = (uint2*)(ws + 2900032);
        uint2*    wl_large  = (uint2*)(ws + 3166272);

        (void)hipMemsetAsync(d_ws, 0, 1581120, stream);
        cov_kernel_a<<<BATCHES * CHUNKS_PER_BATCH, 256, 0, stream>>>(x, S, Msum);
        finalize_kernel<<<(BATCHES * 4096) / 256, 256, 0, stream>>>(S, Msum, tri, hist);
        launch_tail(hist, blocksums, offsets, tri, wl_small, wl_large, counts, out, stream);
    }
}

// Round 6
// 303.513 us; speedup vs baseline: 1.0311x; 1.0311x over previous
//
#include <hip/hip_runtime.h>
#include <hip/hip_bf16.h>
#include <stdint.h>

// CovPool: B=32, N=16384, D=64 fp32 -> per-batch cov (64x64), triu, globally
// sorted 66560 fp32 outputs.
// R13: consolidation. Keep R12's permuted dwordx4 loads (4x fewer VMEM
// requests; cov was request-count latency-bound per R10 PMC), revert R11's
// CHUNKS doubling (partials back to 13.4MB; the doubling cost ~7us+ in
// cov-write + reduce-read and offset the cov gains). Grid 1024, 4 chunks/wave
// with the R7 2-buffer pipeline. Tail = verified R7 hierarchical structure.
//
// Partial-path ws layout:
//   hist      [262144 u32]      @ 0
//   counts    [16 u32]          @ 1048576
//   offsets   [262144 u32]      @ 1048640
//   blocksums [1024 u32]        @ 2097216
//   tri       [66560 f32]       @ 2101312
//   wl_small  [33280 uint2]     @ 2367552
//   wl_large  [4096 uint2]      @ 2633792
//   partials  [1024][2624] f32  @ 2666560  (ends 13414464)

#define BATCHES 32
#define NSAMP   16384
#define DIM     64
#define LAMBDA  0.01f
#define NTRI    2080
#define NOUT    (BATCHES * NTRI)   // 66560

#define CHUNKS_PER_BATCH 32
#define SAMP_PER_BLOCK   (NSAMP / CHUNKS_PER_BATCH)  // 512
#define SAMP_PER_WAVE    (SAMP_PER_BLOCK / 4)        // 128
#define PARTIAL_STRIDE   2624                        // 2560 S + 64 msum

#define KEY_SHIFT 14                                 // top 18 bits
#define NBUCKET   (1 << 18)
#define SMALL_MAX 64u
#define SORT_CAP  8192

typedef __attribute__((ext_vector_type(4))) float f32x4;
typedef __attribute__((ext_vector_type(8))) short s16x8;

__device__ __forceinline__ uint32_t sort_key(float v) {
    uint32_t u = __builtin_bit_cast(uint32_t, v);
    return u ^ (uint32_t)(((int32_t)u >> 31) | 0x80000000u);
}

__device__ __forceinline__ uint32_t cvt_pk_bf16(float lo, float hi) {
    __hip_bfloat162 bb = __float22bfloat162_rn(make_float2(lo, hi));  // v_cvt_pk_bf16_f32
    uint32_t u;
    __builtin_memcpy(&u, &bb, 4);
    return u;
}

// permuted MFMA column index c (= t*16 + l15) -> actual dimension
__device__ __forceinline__ int perm_d(int c) { return 4 * (c & 15) + (c >> 4); }

__constant__ const int c_tmi[10] = {0, 0, 0, 0, 1, 1, 1, 2, 2, 3};
__constant__ const int c_tni[10] = {0, 1, 2, 3, 1, 2, 3, 2, 3, 3};

// ============ shared device body: dwordx4 pipelined MFMA K-loop ==============
struct CovLds {
    float red[2][64][41];     // 20992 B (epilogue tree)
    float msum_red[4][64];    // 1024 B
};

template <typename EpilogueFn>
__device__ __forceinline__ void cov_body(const float* __restrict__ x, CovLds& L,
                                         EpilogueFn epi) {
    const int tid  = threadIdx.x;
    const int wave = tid >> 6;
    const int lane = tid & 63;
    const int b     = blockIdx.x / CHUNKS_PER_BATCH;
    const int chunk = blockIdx.x % CHUNKS_PER_BATCH;
    const int n_start = chunk * SAMP_PER_BLOCK + wave * SAMP_PER_WAVE;

    const int l15  = lane & 15;
    const int quad = lane >> 4;

    // lane (quad,l15) loads x[s0 + quad*8 + j][4*l15 .. 4*l15+3] in ONE
    // dwordx4; element t is permuted column c=t*16+l15 (actual dim 4*l15+t).
    const float* xw = x + ((size_t)b * NSAMP + n_start) * DIM
                        + quad * 8 * DIM + 4 * l15;

    f32x4 acc[10];
#pragma unroll
    for (int t = 0; t < 10; ++t) acc[t] = (f32x4){0.f, 0.f, 0.f, 0.f};
    float sum_t[4] = {0.f, 0.f, 0.f, 0.f};

    f32x4 va[8], vb[8];

    auto loadit = [&](f32x4 (&v)[8], int kc) {
        const float* xs = xw + kc * 32 * DIM;
#pragma unroll
        for (int j = 0; j < 8; ++j)
            v[j] = *reinterpret_cast<const f32x4*>(xs + j * DIM);  // 8 x4 loads
    };

    auto compute = [&](f32x4 (&v)[8]) {
#pragma unroll
        for (int j = 0; j < 8; ++j)
#pragma unroll
            for (int t = 0; t < 4; ++t) sum_t[t] += v[j][t];

        s16x8 frag[4];
#pragma unroll
        for (int t = 0; t < 4; ++t) {
            uint32_t pk0 = cvt_pk_bf16(v[0][t], v[1][t]);
            uint32_t pk1 = cvt_pk_bf16(v[2][t], v[3][t]);
            uint32_t pk2 = cvt_pk_bf16(v[4][t], v[5][t]);
            uint32_t pk3 = cvt_pk_bf16(v[6][t], v[7][t]);
            frag[t] = __builtin_bit_cast(s16x8, make_uint4(pk0, pk1, pk2, pk3));
        }

        acc[0] = __builtin_amdgcn_mfma_f32_16x16x32_bf16(frag[0], frag[0], acc[0], 0, 0, 0);
        acc[1] = __builtin_amdgcn_mfma_f32_16x16x32_bf16(frag[0], frag[1], acc[1], 0, 0, 0);
        acc[2] = __builtin_amdgcn_mfma_f32_16x16x32_bf16(frag[0], frag[2], acc[2], 0, 0, 0);
        acc[3] = __builtin_amdgcn_mfma_f32_16x16x32_bf16(frag[0], frag[3], acc[3], 0, 0, 0);
        acc[4] = __builtin_amdgcn_mfma_f32_16x16x32_bf16(frag[1], frag[1], acc[4], 0, 0, 0);
        acc[5] = __builtin_amdgcn_mfma_f32_16x16x32_bf16(frag[1], frag[2], acc[5], 0, 0, 0);
        acc[6] = __builtin_amdgcn_mfma_f32_16x16x32_bf16(frag[1], frag[3], acc[6], 0, 0, 0);
        acc[7] = __builtin_amdgcn_mfma_f32_16x16x32_bf16(frag[2], frag[2], acc[7], 0, 0, 0);
        acc[8] = __builtin_amdgcn_mfma_f32_16x16x32_bf16(frag[2], frag[3], acc[8], 0, 0, 0);
        acc[9] = __builtin_amdgcn_mfma_f32_16x16x32_bf16(frag[3], frag[3], acc[9], 0, 0, 0);
    };

    // 2-buffer pipeline over SAMP_PER_WAVE/32 = 4 chunks: next chunk's 8
    // x4-loads always in flight behind compute.
    loadit(va, 0);
    loadit(vb, 1);
    compute(va);        // waits only on va's 8 loads
    loadit(va, 2);
    compute(vb);
    loadit(vb, 3);
    compute(va);
    compute(vb);

    // ---- per-dim mean partials (permuted index c = t*16+l15) ----
#pragma unroll
    for (int t = 0; t < 4; ++t) {
        sum_t[t] += __shfl_xor(sum_t[t], 16, 64);
        sum_t[t] += __shfl_xor(sum_t[t], 32, 64);
    }
    if (lane < 16) {
#pragma unroll
        for (int t = 0; t < 4; ++t) L.msum_red[wave][t * 16 + lane] = sum_t[t];
    }

    // ---- in-block tree reduction of 4 waves into wave0 ----
    __syncthreads();
    if (wave == 1 || wave == 3) {
        int slot = wave >> 1;
#pragma unroll
        for (int t = 0; t < 10; ++t)
#pragma unroll
            for (int r = 0; r < 4; ++r) L.red[slot][lane][t * 4 + r] = acc[t][r];
    }
    __syncthreads();
    if (wave == 0 || wave == 2) {
        int slot = wave >> 1;
#pragma unroll
        for (int t = 0; t < 10; ++t)
#pragma unroll
            for (int r = 0; r < 4; ++r) acc[t][r] += L.red[slot][lane][t * 4 + r];
    }
    __syncthreads();
    if (wave == 2) {
#pragma unroll
        for (int t = 0; t < 10; ++t)
#pragma unroll
            for (int r = 0; r < 4; ++r) L.red[0][lane][t * 4 + r] = acc[t][r];
    }
    __syncthreads();
    if (wave == 0) {
#pragma unroll
        for (int t = 0; t < 10; ++t)
#pragma unroll
            for (int r = 0; r < 4; ++r) acc[t][r] += L.red[0][lane][t * 4 + r];
        float msum_tot = L.msum_red[0][lane] + L.msum_red[1][lane] +
                         L.msum_red[2][lane] + L.msum_red[3][lane];
        epi(b, lane, quad, l15, acc, msum_tot);
    }
}

// ---------------- K1p: partial-store variant + hist zeroing ------------------
__global__ __launch_bounds__(256, 3) void cov_kernel_p(const float* __restrict__ x,
                                                       float* __restrict__ partials,
                                                       uint32_t* __restrict__ hist,
                                                       uint32_t* __restrict__ counts) {
    // fold the hist/counts zeroing in: grid 1024 x 256 == 262144 == NBUCKET
    hist[blockIdx.x * 256 + threadIdx.x] = 0u;
    if (blockIdx.x == 0 && threadIdx.x < 16) counts[threadIdx.x] = 0u;

    __shared__ CovLds L;
    float* Pb = partials + (size_t)blockIdx.x * PARTIAL_STRIDE;
    cov_body(x, L, [&](int b, int lane, int quad, int l15, f32x4* acc, float msum) {
#pragma unroll
        for (int t = 0; t < 10; ++t)
#pragma unroll
            for (int r = 0; r < 4; ++r)
                Pb[t * 256 + r * 64 + lane] = acc[t][r];   // coalesced (permuted space)
        Pb[2560 + lane] = msum;
    });
}

// ---------------- K1a: atomic fallback variant -------------------------------
__global__ __launch_bounds__(256, 3) void cov_kernel_a(const float* __restrict__ x,
                                                       float* __restrict__ S,
                                                       float* __restrict__ Msum) {
    __shared__ CovLds L;
    cov_body(x, L, [&](int b, int lane, int quad, int l15, f32x4* acc, float msum) {
        float* Sb = S + b * DIM * DIM;
#pragma unroll
        for (int t = 0; t < 10; ++t) {
            const bool diag_tile = (c_tmi[t] == c_tni[t]);
#pragma unroll
            for (int r = 0; r < 4; ++r) {
                int rp = c_tmi[t] * 16 + quad * 4 + r;   // permuted row
                int cp = c_tni[t] * 16 + l15;            // permuted col
                int ar = perm_d(rp), ac = perm_d(cp);
                if (diag_tile && ar > ac) continue;      // mirror covers it
                int r0 = min(ar, ac), c0 = max(ar, ac);
                atomicAdd(&Sb[r0 * DIM + c0], acc[t][r]);
            }
        }
        atomicAdd(&Msum[b * DIM + perm_d(lane)], msum);
    });
}

// ---------------- K2p: reduce partials + finalize + histogram (320 blocks) ---
__global__ __launch_bounds__(256) void reduce_kernel(const float* __restrict__ partials,
                                                     float* __restrict__ tri,
                                                     uint32_t* __restrict__ hist) {
    const int b = blockIdx.x / 10, k = blockIdx.x % 10;
    const int tid = threadIdx.x;
    __shared__ float msum[DIM];   // permuted-space index
    const float* P0 = partials + (size_t)b * CHUNKS_PER_BATCH * PARTIAL_STRIDE;

    if (tid < DIM) {
        float ms = 0.f;
#pragma unroll
        for (int c = 0; c < CHUNKS_PER_BATCH; ++c)
            ms += P0[c * PARTIAL_STRIDE + 2560 + tid];
        msum[tid] = ms;
    }

    float a = 0.f;
#pragma unroll
    for (int c = 0; c < CHUNKS_PER_BATCH; ++c)
        a += P0[c * PARTIAL_STRIDE + k * 256 + tid];   // coalesced
    __syncthreads();

    const int r = tid >> 6, lane = tid & 63, quad = lane >> 4, l15 = lane & 15;
    const int rp = c_tmi[k] * 16 + quad * 4 + r;       // permuted row
    const int cp = c_tni[k] * 16 + l15;                // permuted col
    const int ar = perm_d(rp), ac = perm_d(cp);        // actual dims
    const bool diag_tile = (c_tmi[k] == c_tni[k]);
    if (!(diag_tile && ar > ac)) {
        const int r0 = min(ar, ac), c0 = max(ar, ac);
        float v = (a - msum[rp] * msum[cp] * (1.0f / NSAMP)) * (1.0f / (NSAMP - 1));
        if (r0 == c0) v += LAMBDA;
        int p = r0 * 64 - (r0 * (r0 + 1)) / 2 + c0;
        tri[b * NTRI + p] = v;
        atomicAdd(&hist[sort_key(v) >> KEY_SHIFT], 1u);
    }
}

// ---------------- K2a: finalize (atomic fallback path) -----------------------
__global__ void finalize_kernel(const float* __restrict__ S,
                                const float* __restrict__ Msum,
                                float* __restrict__ tri,
                                uint32_t* __restrict__ hist) {
    int t = blockIdx.x * blockDim.x + threadIdx.x;
    int b = t >> 12, de = t & 4095, d = de >> 6, e = de & 63;
    if (d > e) return;
    float ssum = S[b * 4096 + d * 64 + e];
    float md = Msum[b * 64 + d], me = Msum[b * 64 + e];
    float v = (ssum - md * me * (1.0f / NSAMP)) * (1.0f / (NSAMP - 1));
    if (d == e) v += LAMBDA;
    int p = d * 64 - (d * (d + 1)) / 2 + e;
    tri[b * NTRI + p] = v;
    atomicAdd(&hist[sort_key(v) >> KEY_SHIFT], 1u);
}

// ---------------- K3a: per-256-bucket partial sums (1024 blocks) -------------
__global__ __launch_bounds__(256) void scanA_kernel(const uint32_t* __restrict__ hist,
                                                    uint32_t* __restrict__ blocksums) {
    __shared__ uint32_t s[256];
    int tid = threadIdx.x;
    s[tid] = hist[blockIdx.x * 256 + tid];
    __syncthreads();
    for (int off = 128; off > 0; off >>= 1) {
        if (tid < off) s[tid] += s[tid + off];
        __syncthreads();
    }
    if (tid == 0) blocksums[blockIdx.x] = s[0];
}

// ---------------- K3b: offsets + worklists (1024 blocks) ---------------------
__global__ __launch_bounds__(256) void scanB_kernel(const uint32_t* __restrict__ hist,
                                                    const uint32_t* __restrict__ blocksums,
                                                    uint32_t* __restrict__ offsets,
                                                    uint2* __restrict__ wl_small,
                                                    uint2* __restrict__ wl_large,
                                                    uint32_t* __restrict__ counts) {
    __shared__ uint32_t bs[256];
    __shared__ uint32_t sc[256];
    __shared__ uint32_t base_sh;
    int tid = threadIdx.x, bid = blockIdx.x;

    uint32_t b4[4]; uint32_t s4 = 0;
#pragma unroll
    for (int i = 0; i < 4; ++i) { b4[i] = blocksums[4 * tid + i]; s4 += b4[i]; }
    bs[tid] = s4;
    __syncthreads();
    for (int off = 1; off < 256; off <<= 1) {
        uint32_t a = (tid >= off) ? bs[tid - off] : 0u;
        __syncthreads();
        bs[tid] += a;
        __syncthreads();
    }
    if (tid == (bid >> 2)) {
        uint32_t base = (tid > 0) ? bs[tid - 1] : 0u;
        for (int i = 0; i < (bid & 3); ++i) base += b4[i];
        base_sh = base;
    }

    uint32_t v = hist[bid * 256 + tid];
    sc[tid] = v;
    __syncthreads();
    for (int off = 1; off < 256; off <<= 1) {
        uint32_t a = (tid >= off) ? sc[tid - off] : 0u;
        __syncthreads();
        sc[tid] += a;
        __syncthreads();
    }
    uint32_t excl = base_sh + sc[tid] - v;
    offsets[bid * 256 + tid] = excl;
    if (v >= 2u) {
        if (v <= SMALL_MAX) {
            uint32_t w = atomicAdd(&counts[0], 1u);
            wl_small[w] = make_uint2(excl, v);
        } else {
            uint32_t w = atomicAdd(&counts[1], 1u);
            wl_large[w] = make_uint2(excl, v);
        }
    }
}

// ---------------- K4: scatter into bucket positions --------------------------
__global__ void scatter_kernel(const float* __restrict__ tri,
                               uint32_t* __restrict__ offsets,
                               float* __restrict__ out) {
    int i = blockIdx.x * blockDim.x + threadIdx.x;
    if (i >= NOUT) return;
    float v = tri[i];
    uint32_t pos = atomicAdd(&offsets[sort_key(v) >> KEY_SHIFT], 1u);
    out[pos] = v;
}

// ---------------- K5: fused run cleanup (block-sort large, wave-sort small) --
__global__ __launch_bounds__(256) void runsort_kernel(float* __restrict__ out,
                                                      const uint2* __restrict__ wl_small,
                                                      const uint2* __restrict__ wl_large,
                                                      const uint32_t* __restrict__ counts) {
    __shared__ float buf[SORT_CAP];

    uint32_t nl = counts[1];
    for (uint32_t w = blockIdx.x; w < nl; w += gridDim.x) {
        uint2 ent = wl_large[w];
        uint32_t start = ent.x, cnt = ent.y;
        if (cnt > SORT_CAP) continue;
        uint32_t m = 1;
        while (m < cnt) m <<= 1;
        for (uint32_t i = threadIdx.x; i < m; i += blockDim.x)
            buf[i] = (i < cnt) ? out[start + i] : __builtin_inff();
        __syncthreads();
        for (uint32_t k = 2; k <= m; k <<= 1) {
            for (uint32_t j = k >> 1; j > 0; j >>= 1) {
                for (uint32_t i = threadIdx.x; i < m; i += blockDim.x) {
                    uint32_t ixj = i ^ j;
                    if (ixj > i) {
                        float a = buf[i], c = buf[ixj];
                        bool up = ((i & k) == 0u);
                        if ((a > c) == up) { buf[i] = c; buf[ixj] = a; }
                    }
                }
                __syncthreads();
            }
        }
        for (uint32_t i = threadIdx.x; i < cnt; i += blockDim.x)
            out[start + i] = buf[i];
        __syncthreads();
    }

    uint32_t ns = counts[0];
    int wave = threadIdx.x >> 6, lane = threadIdx.x & 63;
    for (uint32_t r = blockIdx.x * 4 + wave; r < ns; r += gridDim.x * 4) {
        uint2 e = wl_small[r];
        uint32_t start = e.x, cnt = e.y;
        float v = (lane < (int)cnt) ? out[start + lane] : __builtin_inff();
#pragma unroll
        for (uint32_t k = 2; k <= 64; k <<= 1)
            for (uint32_t j = k >> 1; j > 0; j >>= 1) {
                float p = __shfl_xor(v, (int)j, 64);
                bool keepmin = (((lane & k) == 0u) == ((lane & j) == 0u));
                v = keepmin ? fminf(v, p) : fmaxf(v, p);
            }
        if (lane < (int)cnt) out[start + lane] = v;
    }
}

// ---------------- shared tail launcher ---------------------------------------
static void launch_tail(uint32_t* hist, uint32_t* blocksums, uint32_t* offsets,
                        float* tri, uint2* wl_small, uint2* wl_large,
                        uint32_t* counts, float* out, hipStream_t stream) {
    scanA_kernel<<<NBUCKET / 256, 256, 0, stream>>>(hist, blocksums);
    scanB_kernel<<<NBUCKET / 256, 256, 0, stream>>>(hist, blocksums, offsets,
                                                    wl_small, wl_large, counts);
    scatter_kernel<<<(NOUT + 255) / 256, 256, 0, stream>>>(tri, offsets, out);
    runsort_kernel<<<1024, 256, 0, stream>>>(out, wl_small, wl_large, counts);
}

extern "C" void kernel_launch(void* const* d_in, const int* in_sizes, int n_in,
                              void* d_out, int out_size, void* d_ws, size_t ws_size,
                              hipStream_t stream) {
    const float* x = (const float*)d_in[0];
    float* out = (float*)d_out;
    char* ws = (char*)d_ws;

    const size_t NEED_P =
        2666560 + (size_t)BATCHES * CHUNKS_PER_BATCH * PARTIAL_STRIDE * 4;  // 13.4 MB

    if (ws_size >= NEED_P) {
        uint32_t* hist      = (uint32_t*)(ws);
        uint32_t* counts    = (uint32_t*)(ws + 1048576);
        uint32_t* offsets   = (uint32_t*)(ws + 1048640);
        uint32_t* blocksums = (uint32_t*)(ws + 2097216);
        float*    tri       = (float*)(ws + 2101312);
        uint2*    wl_small  = (uint2*)(ws + 2367552);
        uint2*    wl_large  = (uint2*)(ws + 2633792);
        float*    partials  = (float*)(ws + 2666560);

        // no memset: cov zeroes hist+counts itself
        cov_kernel_p<<<BATCHES * CHUNKS_PER_BATCH, 256, 0, stream>>>(x, partials, hist, counts);
        reduce_kernel<<<BATCHES * 10, 256, 0, stream>>>(partials, tri, hist);
        launch_tail(hist, blocksums, offsets, tri, wl_small, wl_large, counts, out, stream);
    } else {
        float*    S         = (float*)(ws);
        float*    Msum      = (float*)(ws + 524288);
        uint32_t* hist      = (uint32_t*)(ws + 532480);
        uint32_t* counts    = (uint32_t*)(ws + 1581056);
        uint32_t* offsets   = (uint32_t*)(ws + 1581120);
        uint32_t* blocksums = (uint32_t*)(ws + 2629696);
        float*    tri       = (float*)(ws + 2633792);
        uint2*    wl_small  = (uint2*)(ws + 2900032);
        uint2*    wl_large  = (uint2*)(ws + 3166272);

        (void)hipMemsetAsync(d_ws, 0, 1581120, stream);
        cov_kernel_a<<<BATCHES * CHUNKS_PER_BATCH, 256, 0, stream>>>(x, S, Msum);
        finalize_kernel<<<(BATCHES * 4096) / 256, 256, 0, stream>>>(S, Msum, tri, hist);
        launch_tail(hist, blocksums, offsets, tri, wl_small, wl_large, counts, out, stream);
    }
}